// Round 6
// baseline (496.359 us; speedup 1.0000x reference)
//
#include <hip/hip_runtime.h>
#include <math.h>

#define NQ 16384
#define MR 16384
#define JTILES (MR / 16)   // 1024
#define TCHUNK 32          // j-tiles resident in LDS per round (48KB+2KB)

typedef __attribute__((ext_vector_type(8))) short bf16x8;
typedef __attribute__((ext_vector_type(4))) float floatx4;

// round-to-nearest-even fp32 -> bf16 (bit pattern). No NaN/inf in this data.
__device__ __forceinline__ unsigned short bf16_rne(float f) {
    union { float f; unsigned u; } v; v.f = f;
    return (unsigned short)((v.u + 0x7FFFu + ((v.u >> 16) & 1u)) >> 16);
}
__device__ __forceinline__ float bf16_to_f32(unsigned short h) {
    union { unsigned u; float f; } v; v.u = ((unsigned)h) << 16;
    return v.f;
}
// split fp32 v into 3 bf16 terms: v = h + m + l (to ~2^-25 relative)
__device__ __forceinline__ void split3(float v, unsigned short& h,
                                       unsigned short& m, unsigned short& l) {
    h = bf16_rne(v);
    float r1 = v - bf16_to_f32(h);   // exact (Sterbenz)
    m = bf16_rne(r1);
    float r2 = r1 - bf16_to_f32(m);  // exact
    l = bf16_rne(r2);
}
// pack 8 u16 -> one 16B store (dst 16B-aligned)
__device__ __forceinline__ void store8(unsigned short* p, const unsigned short* s) {
    uint4 a;
    a.x = (unsigned)s[0] | ((unsigned)s[1] << 16);
    a.y = (unsigned)s[2] | ((unsigned)s[3] << 16);
    a.z = (unsigned)s[4] | ((unsigned)s[5] << 16);
    a.w = (unsigned)s[6] | ((unsigned)s[7] << 16);
    *(uint4*)p = a;
}

// Main: block = 1024 threads (16 waves), each wave owns 4 query-tiles (64 q).
// Block covers 1024 queries x one j-split. B planes for the split are built
// IN-BLOCK from raw xb into LDS (swizzled fragment layout, same as R5 prep_b:
// element (col,k) of tile t at t*256 + (k>>3)*128 + col*8 + (k&7); R5 measured
// 0 bank conflicts). Hot loop: 32 tiles from LDS, 2 barriers/chunk total.
// Score tile = 3 K-packed MFMAs, acc init = xb2[col]:
//   MFMA1: A=[xh|xm] B=[bh|bh]   MFMA2: A=[xh|xm] B=[bm|bm]
//   MFMA3: A=[xh|xl] B=[bl|bh]   (x planes carry the -2)
// Strict < keeps lowest j on ties. Numerics identical to R4/R5 (absmax 0).
__global__ __launch_bounds__(1024, 8) void nn_mfma(const float* __restrict__ x,
                                                   const float* __restrict__ xb,
                                                   float* __restrict__ pval,
                                                   int* __restrict__ pidx,
                                                   int msplit) {
    __shared__ __align__(16) unsigned short sB[3][TCHUNK * 256];  // 48 KB
    __shared__ float sx2[TCHUNK * 16];                            // 2 KB

    int tid = threadIdx.x;
    int lane = tid & 63;
    int wave = tid >> 6;
    int qt0 = blockIdx.x * 64 + wave * 4;   // 4 q-tiles per wave, 64 per block
    int split = blockIdx.y;
    int JT = JTILES / msplit;               // tiles in this split (>= TCHUNK)
    int t0 = split * JT;

    int n = lane & 15;                      // row (A) / col (B)
    int quad = lane >> 4;
    int halfk = quad & 1;                   // dim half 0..7 / 8..15
    bool low32 = lane < 64 / 2;             // K slot 0..15 vs 16..31
    int eoff2 = halfk * 128 + n * 8;        // shorts, swizzled layout

    // A fragments in-register from raw x (same construction as R4/R5)
    bf16x8 A1[4], A3[4];
#pragma unroll
    for (int q = 0; q < 4; ++q) {
        const float* xr = x + ((size_t)(qt0 + q) * 16 + n) * 16 + halfk * 8;
        float4 u0 = ((const float4*)xr)[0];
        float4 u1 = ((const float4*)xr)[1];
        float e[8] = {u0.x, u0.y, u0.z, u0.w, u1.x, u1.y, u1.z, u1.w};
#pragma unroll
        for (int k = 0; k < 8; ++k) {
            unsigned short h, m, l;
            split3(-2.0f * e[k], h, m, l);
            A1[q][k] = (short)(low32 ? h : m);
            A3[q][k] = (short)(low32 ? h : l);
        }
    }

    const unsigned short* f1b = &sB[0][0];
    const unsigned short* f2b = &sB[1][0];
    const unsigned short* f3b = low32 ? &sB[2][0] : &sB[0][0];

    float best[4][4];
    int bjt[4][4];
#pragma unroll
    for (int q = 0; q < 4; ++q)
#pragma unroll
        for (int r = 0; r < 4; ++r) { best[q][r] = INFINITY; bjt[q][r] = t0; }

    for (int c = 0; c < JT; c += TCHUNK) {
        __syncthreads();   // previous round's reads complete (no-op round 0)
        // In-block B-prep: threads 0..511 each split one ref of this chunk.
        if (tid < TCHUNK * 16) {
            int j = (t0 + c) * 16 + tid;
            const float4* r4 = (const float4*)xb + (size_t)j * 4;
            float4 v0 = r4[0], v1 = r4[1], v2 = r4[2], v3 = r4[3];
            float vals[16] = {v0.x, v0.y, v0.z, v0.w, v1.x, v1.y, v1.z, v1.w,
                              v2.x, v2.y, v2.z, v2.w, v3.x, v3.y, v3.z, v3.w};
            float s0 = v0.x * v0.x + v0.y * v0.y + v0.z * v0.z + v0.w * v0.w;
            float s1 = v1.x * v1.x + v1.y * v1.y + v1.z * v1.z + v1.w * v1.w;
            float s2 = v2.x * v2.x + v2.y * v2.y + v2.z * v2.z + v2.w * v2.w;
            float s3 = v3.x * v3.x + v3.y * v3.y + v3.z * v3.z + v3.w * v3.w;
            sx2[tid] = (s0 + s1) + (s2 + s3);
            unsigned short h[16], m[16], l[16];
#pragma unroll
            for (int k = 0; k < 16; ++k) split3(vals[k], h[k], m[k], l[k]);
            size_t tb = (size_t)(tid >> 4) * 256 + (size_t)(tid & 15) * 8;
            store8(&sB[0][tb], h);  store8(&sB[0][tb + 128], h + 8);
            store8(&sB[1][tb], m);  store8(&sB[1][tb + 128], m + 8);
            store8(&sB[2][tb], l);  store8(&sB[2][tb + 128], l + 8);
        }
        __syncthreads();

#pragma unroll 8
        for (int tt = 0; tt < TCHUNK; ++tt) {
            int tg = t0 + c + tt;                   // global j-tile
            bf16x8 f1 = *(const bf16x8*)(f1b + tt * 256 + eoff2);
            bf16x8 f2 = *(const bf16x8*)(f2b + tt * 256 + eoff2);
            bf16x8 f3 = *(const bf16x8*)(f3b + tt * 256 + eoff2);
            float xv = sx2[tt * 16 + n];
#pragma unroll
            for (int q = 0; q < 4; ++q) {
                floatx4 acc = {xv, xv, xv, xv};
                acc = __builtin_amdgcn_mfma_f32_16x16x32_bf16(A1[q], f1, acc, 0, 0, 0);
                acc = __builtin_amdgcn_mfma_f32_16x16x32_bf16(A1[q], f2, acc, 0, 0, 0);
                acc = __builtin_amdgcn_mfma_f32_16x16x32_bf16(A3[q], f3, acc, 0, 0, 0);
#pragma unroll
                for (int r = 0; r < 4; ++r) {
                    float s = acc[r];
                    if (s < best[q][r]) { best[q][r] = s; bjt[q][r] = tg; }
                }
            }
        }
    }

    // Cross-lane argmin per row (row = quad*4 + r); lex (value, j).
#pragma unroll
    for (int q = 0; q < 4; ++q) {
#pragma unroll
        for (int r = 0; r < 4; ++r) {
            float v = best[q][r];
            int j = bjt[q][r] * 16 + n;
#pragma unroll
            for (int d = 1; d < 16; d <<= 1) {
                float ov = __shfl_xor(v, d, 64);
                int oj = __shfl_xor(j, d, 64);
                if (ov < v || (ov == v && oj < j)) { v = ov; j = oj; }
            }
            if (n == 0) {
                int gq = (qt0 + q) * 16 + quad * 4 + r;
                pval[(size_t)split * NQ + gq] = v;
                pidx[(size_t)split * NQ + gq] = j;
            }
        }
    }
}

// Combine splits (ascending => lowest j wins ties via strict <), gather y.
// 256 blocks x 64 threads -> spread across all CUs, coalesced reads.
__global__ __launch_bounds__(64) void nn_combine(const float* __restrict__ pval,
                                                 const int* __restrict__ pidx,
                                                 const float* __restrict__ y,
                                                 float* __restrict__ out,
                                                 int msplit) {
    int q = blockIdx.x * 64 + threadIdx.x;
    if (q >= NQ) return;
    float bv = INFINITY;
    int bj = 0;
    for (int s = 0; s < msplit; ++s) {
        float v = pval[(size_t)s * NQ + q];
        int id = pidx[(size_t)s * NQ + q];
        if (v < bv) { bv = v; bj = id; }
    }
    out[q] = y[bj];
}

extern "C" void kernel_launch(void* const* d_in, const int* in_sizes, int n_in,
                              void* d_out, int out_size, void* d_ws, size_t ws_size,
                              hipStream_t stream) {
    const float* x  = (const float*)d_in[0];   // [NQ, 16]
    const float* xb = (const float*)d_in[1];   // [MR, 16]
    const float* y  = (const float*)d_in[2];   // [MR]
    float* out = (float*)d_out;                // [NQ]

    // ws need: msplit*NQ*8 (pval+pidx) = 4MB @ msplit=32 (R2 precedent >=4.26MB).
    // Fallback halving: smaller msplit -> JT>TCHUNK handled by chunked LDS rounds.
    int msplit = 32;
    while (msplit > 1 && (size_t)msplit * NQ * 8 > ws_size) msplit >>= 1;

    float* pval = (float*)d_ws;
    int*   pidx = (int*)(pval + (size_t)msplit * NQ);

    dim3 grid(NQ / 1024, msplit);   // 16 x 32 = 512 blocks = 2/CU, 32 waves/CU
    nn_mfma<<<grid, 1024, 0, stream>>>(x, xb, pval, pidx, msplit);
    nn_combine<<<NQ / 64, 64, 0, stream>>>(pval, pidx, y, out, msplit);
}

// Round 7
// 435.589 us; speedup vs baseline: 1.1395x; 1.1395x over previous
//
#include <hip/hip_runtime.h>
#include <math.h>

#define NQ 16384
#define MR 16384
#define JTILES (MR / 16)   // 1024
#define TCHUNK 16          // j-tiles per LDS round (24KB planes + 1KB xb2)

typedef __attribute__((ext_vector_type(8))) short bf16x8;
typedef __attribute__((ext_vector_type(4))) float floatx4;

// round-to-nearest-even fp32 -> bf16 (bit pattern). No NaN/inf in this data.
__device__ __forceinline__ unsigned short bf16_rne(float f) {
    union { float f; unsigned u; } v; v.f = f;
    return (unsigned short)((v.u + 0x7FFFu + ((v.u >> 16) & 1u)) >> 16);
}
__device__ __forceinline__ float bf16_to_f32(unsigned short h) {
    union { unsigned u; float f; } v; v.u = ((unsigned)h) << 16;
    return v.f;
}
// split fp32 v into 3 bf16 terms: v = h + m + l (to ~2^-25 relative)
__device__ __forceinline__ void split3(float v, unsigned short& h,
                                       unsigned short& m, unsigned short& l) {
    h = bf16_rne(v);
    float r1 = v - bf16_to_f32(h);   // exact (Sterbenz)
    m = bf16_rne(r1);
    float r2 = r1 - bf16_to_f32(m);  // exact
    l = bf16_rne(r2);
}
// pack 8 u16 -> one 16B store (dst 16B-aligned)
__device__ __forceinline__ void store8(unsigned short* p, const unsigned short* s) {
    uint4 a;
    a.x = (unsigned)s[0] | ((unsigned)s[1] << 16);
    a.y = (unsigned)s[2] | ((unsigned)s[3] << 16);
    a.z = (unsigned)s[4] | ((unsigned)s[5] << 16);
    a.w = (unsigned)s[6] | ((unsigned)s[7] << 16);
    *(uint4*)p = a;
}

// Main: block = 256 threads (4 waves), each wave owns 4 query-tiles; block
// covers 256 queries x one j-split. B planes built IN-BLOCK from raw xb into
// LDS (swizzled fragment layout: element (col,k) of tile t at t*256 +
// (k>>3)*128 + col*8 + (k&7); R5 measured 0 bank conflicts). One chunk =
// 16 tiles = 256 refs = 1 ref/thread for prep. 2 barriers per 16 tiles.
// Score tile = 3 K-packed MFMAs, acc init = xb2[col]:
//   MFMA1: A=[xh|xm] B=[bh|bh]   MFMA2: A=[xh|xm] B=[bm|bm]
//   MFMA3: A=[xh|xl] B=[bl|bh]   (x planes carry the -2)
// Strict < keeps lowest j on ties. Numerics identical to R4/R5 (absmax 0).
// __launch_bounds__(256,6): VGPR cap 85 >= measured 56 (R5) -> no spill;
// LDS 25.6KB*6 = 153.6/160KB -> 6 blocks/CU = 24 waves/CU.
__global__ __launch_bounds__(256, 6) void nn_mfma(const float* __restrict__ x,
                                                  const float* __restrict__ xb,
                                                  float* __restrict__ pval,
                                                  int* __restrict__ pidx,
                                                  int msplit) {
    __shared__ __align__(16) unsigned short sB[3][TCHUNK * 256];  // 24 KB
    __shared__ float sx2[TCHUNK * 16];                            // 1 KB

    int tid = threadIdx.x;
    int lane = tid & 63;
    int wave = tid >> 6;
    int qt0 = blockIdx.x * 16 + wave * 4;   // 4 q-tiles per wave, 16 per block
    int split = blockIdx.y;
    int JT = JTILES / msplit;               // tiles in this split
    int t0 = split * JT;

    int n = lane & 15;                      // row (A) / col (B)
    int quad = lane >> 4;
    int halfk = quad & 1;                   // dim half 0..7 / 8..15
    bool low32 = lane < 32;                 // K slot 0..15 vs 16..31
    int eoff2 = halfk * 128 + n * 8;        // shorts, swizzled layout

    // A fragments in-register from raw x (same construction as R4/R5)
    bf16x8 A1[4], A3[4];
#pragma unroll
    for (int q = 0; q < 4; ++q) {
        const float* xr = x + ((size_t)(qt0 + q) * 16 + n) * 16 + halfk * 8;
        float4 u0 = ((const float4*)xr)[0];
        float4 u1 = ((const float4*)xr)[1];
        float e[8] = {u0.x, u0.y, u0.z, u0.w, u1.x, u1.y, u1.z, u1.w};
#pragma unroll
        for (int k = 0; k < 8; ++k) {
            unsigned short h, m, l;
            split3(-2.0f * e[k], h, m, l);
            A1[q][k] = (short)(low32 ? h : m);
            A3[q][k] = (short)(low32 ? h : l);
        }
    }

    const unsigned short* f1b = &sB[0][0];
    const unsigned short* f2b = &sB[1][0];
    const unsigned short* f3b = low32 ? &sB[2][0] : &sB[0][0];

    float best[4][4];
    int bjt[4][4];
#pragma unroll
    for (int q = 0; q < 4; ++q)
#pragma unroll
        for (int r = 0; r < 4; ++r) { best[q][r] = INFINITY; bjt[q][r] = t0; }

    for (int c = 0; c < JT; c += TCHUNK) {
        __syncthreads();   // previous round's reads complete (no-op round 0)
        // In-block B-prep: each thread splits one ref of this 256-ref chunk.
        {
            int j = (t0 + c) * 16 + tid;
            const float4* r4 = (const float4*)xb + (size_t)j * 4;
            float4 v0 = r4[0], v1 = r4[1], v2 = r4[2], v3 = r4[3];
            float vals[16] = {v0.x, v0.y, v0.z, v0.w, v1.x, v1.y, v1.z, v1.w,
                              v2.x, v2.y, v2.z, v2.w, v3.x, v3.y, v3.z, v3.w};
            float s0 = v0.x * v0.x + v0.y * v0.y + v0.z * v0.z + v0.w * v0.w;
            float s1 = v1.x * v1.x + v1.y * v1.y + v1.z * v1.z + v1.w * v1.w;
            float s2 = v2.x * v2.x + v2.y * v2.y + v2.z * v2.z + v2.w * v2.w;
            float s3 = v3.x * v3.x + v3.y * v3.y + v3.z * v3.z + v3.w * v3.w;
            sx2[tid] = (s0 + s1) + (s2 + s3);
            unsigned short h[16], m[16], l[16];
#pragma unroll
            for (int k = 0; k < 16; ++k) split3(vals[k], h[k], m[k], l[k]);
            size_t tb = (size_t)(tid >> 4) * 256 + (size_t)(tid & 15) * 8;
            store8(&sB[0][tb], h);  store8(&sB[0][tb + 128], h + 8);
            store8(&sB[1][tb], m);  store8(&sB[1][tb + 128], m + 8);
            store8(&sB[2][tb], l);  store8(&sB[2][tb + 128], l + 8);
        }
        __syncthreads();

#pragma unroll 8
        for (int tt = 0; tt < TCHUNK; ++tt) {
            int tg = t0 + c + tt;                   // global j-tile
            bf16x8 f1 = *(const bf16x8*)(f1b + tt * 256 + eoff2);
            bf16x8 f2 = *(const bf16x8*)(f2b + tt * 256 + eoff2);
            bf16x8 f3 = *(const bf16x8*)(f3b + tt * 256 + eoff2);
            float xv = sx2[tt * 16 + n];
#pragma unroll
            for (int q = 0; q < 4; ++q) {
                floatx4 acc = {xv, xv, xv, xv};
                acc = __builtin_amdgcn_mfma_f32_16x16x32_bf16(A1[q], f1, acc, 0, 0, 0);
                acc = __builtin_amdgcn_mfma_f32_16x16x32_bf16(A1[q], f2, acc, 0, 0, 0);
                acc = __builtin_amdgcn_mfma_f32_16x16x32_bf16(A3[q], f3, acc, 0, 0, 0);
#pragma unroll
                for (int r = 0; r < 4; ++r) {
                    float s = acc[r];
                    if (s < best[q][r]) { best[q][r] = s; bjt[q][r] = tg; }
                }
            }
        }
    }

    // Cross-lane argmin per row (row = quad*4 + r); lex (value, j).
#pragma unroll
    for (int q = 0; q < 4; ++q) {
#pragma unroll
        for (int r = 0; r < 4; ++r) {
            float v = best[q][r];
            int j = bjt[q][r] * 16 + n;
#pragma unroll
            for (int d = 1; d < 16; d <<= 1) {
                float ov = __shfl_xor(v, d, 64);
                int oj = __shfl_xor(j, d, 64);
                if (ov < v || (ov == v && oj < j)) { v = ov; j = oj; }
            }
            if (n == 0) {
                int gq = (qt0 + q) * 16 + quad * 4 + r;
                pval[(size_t)split * NQ + gq] = v;
                pidx[(size_t)split * NQ + gq] = j;
            }
        }
    }
}

// Combine splits (ascending => lowest j wins ties via strict <), gather y.
__global__ __launch_bounds__(64) void nn_combine(const float* __restrict__ pval,
                                                 const int* __restrict__ pidx,
                                                 const float* __restrict__ y,
                                                 float* __restrict__ out,
                                                 int msplit) {
    int q = blockIdx.x * 64 + threadIdx.x;
    if (q >= NQ) return;
    float bv = INFINITY;
    int bj = 0;
    for (int s = 0; s < msplit; ++s) {
        float v = pval[(size_t)s * NQ + q];
        int id = pidx[(size_t)s * NQ + q];
        if (v < bv) { bv = v; bj = id; }
    }
    out[q] = y[bj];
}

extern "C" void kernel_launch(void* const* d_in, const int* in_sizes, int n_in,
                              void* d_out, int out_size, void* d_ws, size_t ws_size,
                              hipStream_t stream) {
    const float* x  = (const float*)d_in[0];   // [NQ, 16]
    const float* xb = (const float*)d_in[1];   // [MR, 16]
    const float* y  = (const float*)d_in[2];   // [MR]
    float* out = (float*)d_out;                // [NQ]

    // ws need: msplit*NQ*8 (pval+pidx) = 4MB @ msplit=32 (R2 precedent >=4.26MB).
    int msplit = 32;
    while (msplit > 1 && (size_t)msplit * NQ * 8 > ws_size) msplit >>= 1;

    float* pval = (float*)d_ws;
    int*   pidx = (int*)(pval + (size_t)msplit * NQ);

    dim3 grid(NQ / 256, msplit);   // 64 x 32 = 2048 blocks
    nn_mfma<<<grid, 256, 0, stream>>>(x, xb, pval, pidx, msplit);
    nn_combine<<<NQ / 64, 64, 0, stream>>>(pval, pidx, y, out, msplit);
}

// Round 8
// 128.878 us; speedup vs baseline: 3.8514x; 3.3799x over previous
//
#include <hip/hip_runtime.h>
#include <math.h>

#define NQ 16384
#define MR 16384
#define JTILES (MR / 16)   // 1024
#define MSPLIT 32
#define JT (JTILES / MSPLIT)  // 32 j-tiles per split
#define CHUNK 8            // j-tiles staged per LDS round (12.3 KB)

typedef __attribute__((ext_vector_type(8))) short bf16x8;
typedef __attribute__((ext_vector_type(4))) float floatx4;

// round-to-nearest-even fp32 -> bf16 (bit pattern). No NaN/inf in this data.
__device__ __forceinline__ unsigned short bf16_rne(float f) {
    union { float f; unsigned u; } v; v.f = f;
    return (unsigned short)((v.u + 0x7FFFu + ((v.u >> 16) & 1u)) >> 16);
}
__device__ __forceinline__ float bf16_to_f32(unsigned short h) {
    union { unsigned u; float f; } v; v.u = ((unsigned)h) << 16;
    return v.f;
}
// split fp32 v into 3 bf16 terms: v = h + m + l (to ~2^-25 relative)
__device__ __forceinline__ void split3(float v, unsigned short& h,
                                       unsigned short& m, unsigned short& l) {
    h = bf16_rne(v);
    float r1 = v - bf16_to_f32(h);   // exact (Sterbenz)
    m = bf16_rne(r1);
    float r2 = r1 - bf16_to_f32(m);  // exact
    l = bf16_rne(r2);
}
// pack 8 u16 -> one 16B store (dst 16B-aligned)
__device__ __forceinline__ void store8(unsigned short* p, const unsigned short* s) {
    uint4 a;
    a.x = (unsigned)s[0] | ((unsigned)s[1] << 16);
    a.y = (unsigned)s[2] | ((unsigned)s[3] << 16);
    a.z = (unsigned)s[4] | ((unsigned)s[5] << 16);
    a.w = (unsigned)s[6] | ((unsigned)s[7] << 16);
    *(uint4*)p = a;
}
// monotone fp32 -> u32 (total order preserving; no NaNs in this data)
__device__ __forceinline__ unsigned fmap(float f) {
    union { float f; unsigned u; } v; v.f = f;
    return (v.u & 0x80000000u) ? ~v.u : (v.u | 0x80000000u);
}

// Prep (separate kernel so its fat live-set never shares a budget with the
// MFMA loop — R6/R7 spill lesson): split xb into 3 bf16 planes in swizzled
// B-fragment order (element (col,k) of tile t at t*256 + (k>>3)*128 + col*8
// + (k&7); 0 bank conflicts measured R5), xb2 = ||xb||^2 (same tree order as
// R2..R7 passing), and init keys[j] = max (NQ==MR; re-done every launch since
// harness re-poisons ws).
__global__ __launch_bounds__(256) void prep_b(const float* __restrict__ xb,
                                              unsigned short* __restrict__ BH,
                                              unsigned short* __restrict__ BM,
                                              unsigned short* __restrict__ BL,
                                              float* __restrict__ xb2,
                                              unsigned long long* __restrict__ keys) {
    int j = blockIdx.x * 256 + threadIdx.x;
    keys[j] = 0xFFFFFFFFFFFFFFFFull;
    const float4* r4 = (const float4*)xb + (size_t)j * 4;
    float4 v0 = r4[0], v1 = r4[1], v2 = r4[2], v3 = r4[3];
    float vals[16] = {v0.x, v0.y, v0.z, v0.w, v1.x, v1.y, v1.z, v1.w,
                      v2.x, v2.y, v2.z, v2.w, v3.x, v3.y, v3.z, v3.w};
    float s0 = v0.x * v0.x + v0.y * v0.y + v0.z * v0.z + v0.w * v0.w;
    float s1 = v1.x * v1.x + v1.y * v1.y + v1.z * v1.z + v1.w * v1.w;
    float s2 = v2.x * v2.x + v2.y * v2.y + v2.z * v2.z + v2.w * v2.w;
    float s3 = v3.x * v3.x + v3.y * v3.y + v3.z * v3.z + v3.w * v3.w;
    xb2[j] = (s0 + s1) + (s2 + s3);
    unsigned short h[16], m[16], l[16];
#pragma unroll
    for (int k = 0; k < 16; ++k) split3(vals[k], h[k], m[k], l[k]);
    size_t tb = (size_t)(j >> 4) * 256 + (size_t)(j & 15) * 8;
    store8(BH + tb, h);       store8(BH + tb + 128, h + 8);
    store8(BM + tb, m);       store8(BM + tb + 128, m + 8);
    store8(BL + tb, l);       store8(BL + tb + 128, l + 8);
}

// Main: R5's proven hot loop (56 VGPR, absmax 0). Per wave 4 query-tiles;
// block = 4 waves = 16 q-tiles = 256 queries x one j-split (32 tiles).
// B fragments staged chunk-wise (8 tiles) into LDS. Score tile = 3 K-packed
// MFMAs, acc init = xb2[col]:
//   MFMA1: A=[xh|xm] B=[bh|bh]   MFMA2: A=[xh|xm] B=[bm|bm]
//   MFMA3: A=[xh|xl] B=[bl|bh]   (x planes carry the -2)
// Epilogue: lex (value, j) wave-reduce then one atomicMin per row with
// key = fmap(v)<<32 | j  — exact same winner as R5's pval/pidx+combine.
// Grid 64x32 = 2048 blocks = 8/CU; LDS 12.3KB*8 = 98KB; VGPR ~56 <= 64
// -> 32 waves/CU.
__global__ __launch_bounds__(256, 4) void nn_mfma(const float* __restrict__ x,
                                                  const unsigned short* __restrict__ BH,
                                                  const unsigned short* __restrict__ BM,
                                                  const unsigned short* __restrict__ BL,
                                                  const float* __restrict__ xb2,
                                                  unsigned long long* __restrict__ keys) {
    __shared__ __align__(16) unsigned short sB[3][CHUNK * 256];   // 12 KB

    int tid = threadIdx.x;
    int lane = tid & 63;
    int wave = tid >> 6;
    int qt0 = blockIdx.x * 16 + wave * 4;          // 4 q-tiles per wave
    int split = blockIdx.y;
    int t0 = split * JT;

    int n = lane & 15;                              // row (A) / col (B)
    int quad = lane >> 4;
    int halfk = quad & 1;                           // dim half 0..7 / 8..15
    bool low32 = lane < 32;                         // K slot 0..15 vs 16..31
    int eoff2 = halfk * 128 + n * 8;                // shorts, swizzled layout

    // A fragments in-register from raw x (same construction as R4/R5)
    bf16x8 A1[4], A3[4];
#pragma unroll
    for (int q = 0; q < 4; ++q) {
        const float* xr = x + ((size_t)(qt0 + q) * 16 + n) * 16 + halfk * 8;
        float4 u0 = ((const float4*)xr)[0];
        float4 u1 = ((const float4*)xr)[1];
        float e[8] = {u0.x, u0.y, u0.z, u0.w, u1.x, u1.y, u1.z, u1.w};
#pragma unroll
        for (int k = 0; k < 8; ++k) {
            unsigned short h, m, l;
            split3(-2.0f * e[k], h, m, l);
            A1[q][k] = (short)(low32 ? h : m);
            A3[q][k] = (short)(low32 ? h : l);
        }
    }

    const unsigned short* f1b = &sB[0][0];
    const unsigned short* f2b = &sB[1][0];
    const unsigned short* f3b = low32 ? &sB[2][0] : &sB[0][0];
    const float* pxv = xb2 + t0 * 16 + n;

    float best[4][4];
    int bjt[4][4];
#pragma unroll
    for (int q = 0; q < 4; ++q)
#pragma unroll
        for (int r = 0; r < 4; ++r) { best[q][r] = INFINITY; bjt[q][r] = t0; }

    for (int c = 0; c < JT; c += CHUNK) {
        __syncthreads();   // previous round's reads complete (no-op round 0)
        // stage CHUNK tiles x 3 planes: 256 threads x 16B per plane
        {
            size_t gb = (size_t)(t0 + c) * 256 + (size_t)tid * 8;
            uint4 hV = *(const uint4*)(BH + gb);
            uint4 mV = *(const uint4*)(BM + gb);
            uint4 lV = *(const uint4*)(BL + gb);
            ((uint4*)&sB[0][0])[tid] = hV;
            ((uint4*)&sB[1][0])[tid] = mV;
            ((uint4*)&sB[2][0])[tid] = lV;
        }
        __syncthreads();

#pragma unroll
        for (int tt = 0; tt < CHUNK; ++tt) {
            int tg = t0 + c + tt;                   // global j-tile
            bf16x8 f1 = *(const bf16x8*)(f1b + tt * 256 + eoff2);
            bf16x8 f2 = *(const bf16x8*)(f2b + tt * 256 + eoff2);
            bf16x8 f3 = *(const bf16x8*)(f3b + tt * 256 + eoff2);
            float xv = pxv[(c + tt) * 16];
#pragma unroll
            for (int q = 0; q < 4; ++q) {
                floatx4 acc = {xv, xv, xv, xv};
                acc = __builtin_amdgcn_mfma_f32_16x16x32_bf16(A1[q], f1, acc, 0, 0, 0);
                acc = __builtin_amdgcn_mfma_f32_16x16x32_bf16(A1[q], f2, acc, 0, 0, 0);
                acc = __builtin_amdgcn_mfma_f32_16x16x32_bf16(A3[q], f3, acc, 0, 0, 0);
#pragma unroll
                for (int r = 0; r < 4; ++r) {
                    float s = acc[r];
                    if (s < best[q][r]) { best[q][r] = s; bjt[q][r] = tg; }
                }
            }
        }
    }

    // Cross-lane argmin per row (row = quad*4 + r); lex (value, j);
    // one device-scope atomicMin per row with the packed order-key.
#pragma unroll
    for (int q = 0; q < 4; ++q) {
#pragma unroll
        for (int r = 0; r < 4; ++r) {
            float v = best[q][r];
            int j = bjt[q][r] * 16 + n;
#pragma unroll
            for (int d = 1; d < 16; d <<= 1) {
                float ov = __shfl_xor(v, d, 64);
                int oj = __shfl_xor(j, d, 64);
                if (ov < v || (ov == v && oj < j)) { v = ov; j = oj; }
            }
            if (n == 0) {
                int gq = (qt0 + q) * 16 + quad * 4 + r;
                unsigned long long key =
                    ((unsigned long long)fmap(v) << 32) | (unsigned)j;
                atomicMin(&keys[gq], key);
            }
        }
    }
}

// Decode keys -> y gather.
__global__ __launch_bounds__(256) void nn_decode(const unsigned long long* __restrict__ keys,
                                                 const float* __restrict__ y,
                                                 float* __restrict__ out) {
    int q = blockIdx.x * 256 + threadIdx.x;
    if (q >= NQ) return;
    out[q] = y[(unsigned)(keys[q] & 0xFFFFFFFFu)];
}

extern "C" void kernel_launch(void* const* d_in, const int* in_sizes, int n_in,
                              void* d_out, int out_size, void* d_ws, size_t ws_size,
                              hipStream_t stream) {
    const float* x  = (const float*)d_in[0];   // [NQ, 16]
    const float* xb = (const float*)d_in[1];   // [MR, 16]
    const float* y  = (const float*)d_in[2];   // [MR]
    float* out = (float*)d_out;                // [NQ]

    // ws: planes 3*MR*16*2 = 1.5MB + xb2 64KB + keys NQ*8 = 128KB -> 1.7MB
    unsigned short* BH = (unsigned short*)d_ws;
    unsigned short* BM = BH + (size_t)MR * 16;
    unsigned short* BL = BM + (size_t)MR * 16;
    float* xb2 = (float*)(BL + (size_t)MR * 16);
    unsigned long long* keys = (unsigned long long*)(xb2 + MR);

    prep_b<<<MR / 256, 256, 0, stream>>>(xb, BH, BM, BL, xb2, keys);
    dim3 grid(NQ / 256, MSPLIT);               // 64 x 32 = 2048 blocks, 8/CU
    nn_mfma<<<grid, 256, 0, stream>>>(x, BH, BM, BL, xb2, keys);
    nn_decode<<<NQ / 256, 256, 0, stream>>>(keys, y, out);
}